// Round 9
// baseline (548.627 us; speedup 1.0000x reference)
//
#include <hip/hip_runtime.h>
#include <hip/hip_bf16.h>

using bf16 = __hip_bfloat16;
typedef __attribute__((ext_vector_type(8))) short bf16x8;
typedef __attribute__((ext_vector_type(4))) float f32x4;

#define DDIM 1024

__device__ __forceinline__ void gload16(const bf16* g, bf16* l) {
    __builtin_amdgcn_global_load_lds(
        (const __attribute__((address_space(1))) void*)g,
        (__attribute__((address_space(3))) void*)l, 16, 0, 0);
}
__device__ __forceinline__ short f2b(float f) {
    return (short)__bfloat16_as_ushort(__float2bfloat16(f));
}

__global__ void prep_kernel(const float* __restrict__ W, const float* __restrict__ w,
                            const float* __restrict__ b, const float* __restrict__ nstr,
                            const float* __restrict__ nraw,
                            float* __restrict__ dco, float* __restrict__ ad2,
                            bf16* __restrict__ Wb) {
    int o = blockIdx.x;
    int lane = threadIdx.x;
    const float* Wrow = W + (size_t)o * DDIM;
    bf16* Wbrow = Wb + (size_t)o * DDIM;
    float s = 0.f;
    for (int j = lane; j < DDIM; j += 64) {
        float wv = Wrow[j];
        Wbrow[j] = __float2bfloat16(wv);
        float m = wv * w[j];
        s += m * m;
    }
#pragma unroll
    for (int off = 32; off; off >>= 1) s += __shfl_down(s, off);
    if (lane == 0) {
        dco[o] = rsqrtf(s + 1e-8f);
        ad2[o] = nraw[o] * nstr[0] + b[o];
    }
}

// ---- 256x256x(BK=64) GEMM, C[n][o] = sum_j A[n][j]*W[o][j] ----
// A staged in LDS (double-buffered, 64 KiB); B (=W, 2 MB, L2-resident) read
// DIRECTLY from global into registers (same fragment mapping the LDS path had).
// One __syncthreads per K-tile: its vmcnt(0) drain targets loads issued a full
// tile (~2500 cyc) earlier, so HBM/L2 latency is covered structurally.
template<int PASS>
__global__ __launch_bounds__(512, 2) void gemmS(
    const float* __restrict__ Af, const bf16* __restrict__ Ab,
    const bf16* __restrict__ Bw,
    const float* __restrict__ wst, const float* __restrict__ bias,
    const float* __restrict__ dco, const float* __restrict__ ad2,
    bf16* __restrict__ Cb, float* __restrict__ Cf)
{
    __shared__ bf16 sA[2][2][256 * 32];   // [buf][ks][256 rows x 32 K], 64 KiB

    const int tid  = threadIdx.x;
    const int lane = tid & 63;
    const int wid  = tid >> 6;
    const int wr   = wid >> 2, wc = wid & 3;      // 2 x 4 waves, wave owns 128x64
    const int r16  = lane & 15, kh = lane >> 4;
    const int fso  = (kh ^ ((r16 >> 1) & 3)) * 8; // swizzled frag slot (elems)

    int bx  = blockIdx.x;                          // 1024 blocks
    int swz = (bx & 7) * 128 + (bx >> 3);          // bijective XCD swizzle
    int brow = swz >> 2, bcol = swz & 3;

    const float* Asrc_f = Af + (size_t)(brow * 256) * DDIM;
    const bf16*  Asrc_b = Ab + (size_t)(brow * 256) * DDIM;
    // per-lane B fragment base: row = bcol*256 + wc*64 + n*16 + r16, k-chunk kh*8
    const bf16*  BsW = Bw + (size_t)(bcol * 256 + wc * 64 + r16) * DDIM + kh * 8;

    const int sr  = tid >> 2;                      // staging row 0..127 (and +128)
    const int ssl = (tid & 3) ^ ((sr >> 1) & 3);   // swizzled 16B slot

    f32x4 acc[8][4];
#pragma unroll
    for (int m = 0; m < 8; ++m)
#pragma unroll
        for (int n = 0; n < 4; ++n) acc[m][n] = (f32x4){0.f, 0.f, 0.f, 0.f};

    bf16x8 aF[4];
    bf16x8 bX0[4], bX1[4], bY0[4], bY1[4];   // B regs: two tile-groups x two K-halves

// stage A K-tile kt into sA[buf] (PASS2: gload_lds; PASS1: fp32 load+cvt+ds_write)
#define STAGE_A(buf, kt) do { \
    if constexpr (PASS == 1) { \
        _Pragma("unroll") for (int _ks = 0; _ks < 2; ++_ks) { \
            const float* _p = Asrc_f + (size_t)sr * DDIM + (kt) * 64 + _ks * 32 + (tid & 3) * 8; \
            float4 _v0 = ((const float4*)_p)[0], _v1 = ((const float4*)_p)[1]; \
            const float* _q = _p + 128 * DDIM; \
            float4 _v2 = ((const float4*)_q)[0], _v3 = ((const float4*)_q)[1]; \
            bf16x8 _pk; \
            _pk[0]=f2b(_v0.x); _pk[1]=f2b(_v0.y); _pk[2]=f2b(_v0.z); _pk[3]=f2b(_v0.w); \
            _pk[4]=f2b(_v1.x); _pk[5]=f2b(_v1.y); _pk[6]=f2b(_v1.z); _pk[7]=f2b(_v1.w); \
            *(bf16x8*)&sA[buf][_ks][sr * 32 + ssl * 8] = _pk; \
            _pk[0]=f2b(_v2.x); _pk[1]=f2b(_v2.y); _pk[2]=f2b(_v2.z); _pk[3]=f2b(_v2.w); \
            _pk[4]=f2b(_v3.x); _pk[5]=f2b(_v3.y); _pk[6]=f2b(_v3.z); _pk[7]=f2b(_v3.w); \
            *(bf16x8*)&sA[buf][_ks][(sr + 128) * 32 + ssl * 8] = _pk; \
        } \
    } else { \
        _Pragma("unroll") for (int _ks = 0; _ks < 2; ++_ks) { \
            const bf16* _s = Asrc_b + (size_t)sr * DDIM + (kt) * 64 + _ks * 32 + ssl * 8; \
            gload16(_s,              &sA[buf][_ks][tid * 8]); \
            gload16(_s + 128 * DDIM, &sA[buf][_ks][(tid + 512) * 8]); \
        } \
    } \
} while (0)

// load B fragments for K-tile kt into (d0 = ks0, d1 = ks1)
#define LOAD_B(d0, d1, kt) do { \
    _Pragma("unroll") for (int _n = 0; _n < 4; ++_n) { \
        const bf16* _b = BsW + (size_t)_n * 16 * DDIM + (kt) * 64; \
        d0[_n] = *(const bf16x8*)_b; \
        d1[_n] = *(const bf16x8*)(_b + 32); \
    } \
} while (0)

#define RD_A(buf, ks, mh) do { \
    _Pragma("unroll") for (int _m = 0; _m < 4; ++_m) \
        aF[_m] = *(const bf16x8*)&sA[buf][ks][(wr * 128 + (mh) * 64 + _m * 16 + r16) * 32 + fso]; \
} while (0)

#define MFMAQ(base, B) do { \
    _Pragma("unroll") for (int _m = 0; _m < 4; ++_m) \
    _Pragma("unroll") for (int _n = 0; _n < 4; ++_n) \
        acc[(base)+_m][_n] = __builtin_amdgcn_mfma_f32_16x16x32_bf16(aF[_m], B[_n], acc[(base)+_m][_n], 0, 0, 0); \
} while (0)

// full K-tile: 16 ds_read_b128 + 64 MFMA per wave, compiler-scheduled
#define TILE_COMPUTE(buf, B0, B1) do { \
    RD_A(buf, 0, 0); MFMAQ(0, B0); \
    RD_A(buf, 0, 1); MFMAQ(4, B0); \
    RD_A(buf, 1, 0); MFMAQ(0, B1); \
    RD_A(buf, 1, 1); MFMAQ(4, B1); \
} while (0)

    // ---------------- prologue ----------------
    STAGE_A(0, 0);
    LOAD_B(bX0, bX1, 0);
    __syncthreads();

    // ---------------- main loop: 8 iters x 2 K-tiles ----------------
    for (int i = 0; i < 8; ++i) {
        int tB = 2 * i + 1;

        // tile 2i (buf0, bX); prefetch tile 2i+1 -> buf1, bY
        STAGE_A(1, tB);
        LOAD_B(bY0, bY1, tB);
        TILE_COMPUTE(0, bX0, bX1);
        __syncthreads();

        // tile 2i+1 (buf1, bY); prefetch tile 2i+2 -> buf0, bX
        if (i < 7) {
            STAGE_A(0, tB + 1);
            LOAD_B(bX0, bX1, tB + 1);
        }
        TILE_COMPUTE(1, bY0, bY1);
        __syncthreads();
    }

    // ---------------- epilogue ----------------
    int crb = brow * 256 + wr * 128 + kh * 4;
    int ccb = bcol * 256 + wc * 64 + r16;
#pragma unroll
    for (int n = 0; n < 4; ++n) {
        int col = ccb + n * 16;
        float cm, ca;
        if constexpr (PASS == 1) { cm = wst[col]; ca = bias[col]; }
        else                     { cm = dco[col]; ca = ad2[col]; }
#pragma unroll
        for (int m = 0; m < 8; ++m) {
#pragma unroll
            for (int j = 0; j < 4; ++j) {
                size_t idx = (size_t)(crb + m * 16 + j) * DDIM + col;
                float v = acc[m][n][j];
                if constexpr (PASS == 1) {
                    v = (v + ca) * cm;
                    Cb[idx] = __float2bfloat16(v);
                } else {
                    v = v * cm + ca;
                    v = (v >= 0.f) ? v : 0.01f * v;
                    Cf[idx] = v;
                }
            }
        }
    }
#undef STAGE_A
#undef LOAD_B
#undef RD_A
#undef MFMAQ
#undef TILE_COMPUTE
}

extern "C" void kernel_launch(void* const* d_in, const int* in_sizes, int n_in,
                              void* d_out, int out_size, void* d_ws, size_t ws_size,
                              hipStream_t stream) {
    const float* x  = (const float*)d_in[0];
    const float* w  = (const float*)d_in[1];
    const float* W  = (const float*)d_in[2];
    const float* b  = (const float*)d_in[3];
    const float* ns = (const float*)d_in[4];
    const float* nr = (const float*)d_in[5];
    float* out = (float*)d_out;

    float* dco = (float*)d_ws;
    float* ad2 = dco + DDIM;
    bf16*  Wb  = (bf16*)((char*)d_ws + 8192);
    bf16*  t   = (bf16*)((char*)d_ws + 8192 + 2097152);

    int M = in_sizes[0] / DDIM;                     // 65536
    int grid = (M / 256) * (DDIM / 256);            // 1024

    prep_kernel<<<DDIM, 64, 0, stream>>>(W, w, b, ns, nr, dco, ad2, Wb);
    gemmS<1><<<grid, 512, 0, stream>>>(x, nullptr, Wb, w, b, dco, ad2, t, nullptr);
    gemmS<2><<<grid, 512, 0, stream>>>(nullptr, t, Wb, w, b, dco, ad2, nullptr, out);
}

// Round 10
// 416.073 us; speedup vs baseline: 1.3186x; 1.3186x over previous
//
#include <hip/hip_runtime.h>
#include <hip/hip_bf16.h>

using bf16 = __hip_bfloat16;
typedef __attribute__((ext_vector_type(8)))  short bf16x8;
typedef __attribute__((ext_vector_type(4)))  float f32x4;
typedef __attribute__((ext_vector_type(16))) float f32x16;

#define DDIM 1024

__device__ __forceinline__ void gload16(const bf16* g, bf16* l) {
    __builtin_amdgcn_global_load_lds(
        (const __attribute__((address_space(1))) void*)g,
        (__attribute__((address_space(3))) void*)l, 16, 0, 0);
}
__device__ __forceinline__ short f2b(float f) {
    return (short)__bfloat16_as_ushort(__float2bfloat16(f));
}

__global__ void prep_kernel(const float* __restrict__ W, const float* __restrict__ w,
                            const float* __restrict__ b, const float* __restrict__ nstr,
                            const float* __restrict__ nraw,
                            float* __restrict__ dco, float* __restrict__ ad2,
                            bf16* __restrict__ Wb) {
    int o = blockIdx.x;
    int lane = threadIdx.x;
    const float* Wrow = W + (size_t)o * DDIM;
    bf16* Wbrow = Wb + (size_t)o * DDIM;
    float s = 0.f;
    for (int j = lane; j < DDIM; j += 64) {
        float wv = Wrow[j];
        Wbrow[j] = __float2bfloat16(wv);
        float m = wv * w[j];
        s += m * m;
    }
#pragma unroll
    for (int off = 32; off; off >>= 1) s += __shfl_down(s, off);
    if (lane == 0) {
        dco[o] = rsqrtf(s + 1e-8f);
        ad2[o] = nraw[o] * nstr[0] + b[o];
    }
}

// ---- 256x256x(BK=64) 8-phase GEMM, C[n][o] = sum_j A[n][j]*W[o][j] ----
// R8 structure exactly; compute core switched 16x16x32 -> 32x32x16 (m119 best shape:
// 2495 TF vs 2075; half the MFMA instructions for the same work, same LDS traffic).
// A frag: row=lane&31, k-chunk=(lane>>5)*8.  C/D: col=lane&31,
// row=(reg&3)+8*(reg>>2)+4*(lane>>5)  [m74/m101 verified].
#define BAR()  __builtin_amdgcn_s_barrier()
#define VMW(n) asm volatile("s_waitcnt vmcnt(" #n ")")
#define LGW()  asm volatile("s_waitcnt lgkmcnt(0)")

template<int PASS>
__global__ __launch_bounds__(512, 2) void gemm32(
    const float* __restrict__ Af, const bf16* __restrict__ Ab,
    const bf16* __restrict__ Bw,
    const float* __restrict__ wst, const float* __restrict__ bias,
    const float* __restrict__ dco, const float* __restrict__ ad2,
    bf16* __restrict__ Cb, float* __restrict__ Cf)
{
    __shared__ bf16 sA[2][2][256 * 32];   // [buf][ks32][256 rows x 32 K], 64 KiB
    __shared__ bf16 sB[2][2][256 * 32];   // 64 KiB

    const int tid  = threadIdx.x;
    const int lane = tid & 63;
    const int wid  = tid >> 6;
    const int wr   = wid >> 2, wc = wid & 3;      // 2 x 4 waves, wave owns 128x64
    const int l31  = lane & 31, lh = lane >> 5;   // 32x32 frag coords

    int bx  = blockIdx.x;                          // 1024 blocks
    int swz = (bx & 7) * 128 + (bx >> 3);          // bijective XCD swizzle
    int brow = swz >> 2, bcol = swz & 3;

    const float* Asrc_f = Af + (size_t)(brow * 256) * DDIM;
    const bf16*  Asrc_b = Ab + (size_t)(brow * 256) * DDIM;
    const bf16*  Bsrc   = Bw + (size_t)(bcol * 256) * DDIM;

    const int sr  = tid >> 2;                      // staging row 0..127 (and +128)
    const int ssl = (tid & 3) ^ ((sr >> 1) & 3);   // swizzled 16B source slot

    f32x16 acc[4][2];                              // [mt 0..3 over 128 rows][nt 0..1 over 64 cols]
#pragma unroll
    for (int m = 0; m < 4; ++m)
#pragma unroll
        for (int n = 0; n < 2; ++n)
#pragma unroll
            for (int r = 0; r < 16; ++r) acc[m][n][r] = 0.f;

    bf16x8 aK0[2], aK1[2], bK0[2], bK1[2];         // frags: [mt|nt], ks16 = 0/1
    float4 gA0, gA1, gA2, gA3;                     // PASS1 A-prefetch regs (K-half 0)
    float4 gB0, gB1, gB2, gB3;                     // PASS1 A-prefetch regs (K-half 1)

#define STAGE_B(buf, kt, ks) do { \
    const bf16* _s = Bsrc + (size_t)sr * DDIM + ((kt) * 64 + (ks) * 32 + ssl * 8); \
    gload16(_s,               &sB[buf][ks][tid * 8]); \
    gload16(_s + 128 * DDIM,  &sB[buf][ks][(tid + 512) * 8]); \
} while (0)

#define STAGE_A_G(buf, kt, ks) do { \
    const bf16* _s = Asrc_b + (size_t)sr * DDIM + ((kt) * 64 + (ks) * 32 + ssl * 8); \
    gload16(_s,               &sA[buf][ks][tid * 8]); \
    gload16(_s + 128 * DDIM,  &sA[buf][ks][(tid + 512) * 8]); \
} while (0)

#define LOAD_A_F(g0, g1, g2, g3, kt, ks) do { \
    const float* _p = Asrc_f + (size_t)sr * DDIM + ((kt) * 64 + (ks) * 32 + (tid & 3) * 8); \
    g0 = ((const float4*)_p)[0]; g1 = ((const float4*)_p)[1]; \
    const float* _q = _p + 128 * DDIM; \
    g2 = ((const float4*)_q)[0]; g3 = ((const float4*)_q)[1]; \
} while (0)

#define WRITE_A(buf, ks, g0, g1, g2, g3) do { \
    bf16x8 _pk; \
    _pk[0]=f2b(g0.x); _pk[1]=f2b(g0.y); _pk[2]=f2b(g0.z); _pk[3]=f2b(g0.w); \
    _pk[4]=f2b(g1.x); _pk[5]=f2b(g1.y); _pk[6]=f2b(g1.z); _pk[7]=f2b(g1.w); \
    *(bf16x8*)&sA[buf][ks][sr * 32 + ssl * 8] = _pk; \
    _pk[0]=f2b(g2.x); _pk[1]=f2b(g2.y); _pk[2]=f2b(g2.z); _pk[3]=f2b(g2.w); \
    _pk[4]=f2b(g3.x); _pk[5]=f2b(g3.y); _pk[6]=f2b(g3.z); _pk[7]=f2b(g3.w); \
    *(bf16x8*)&sA[buf][ks][(sr + 128) * 32 + ssl * 8] = _pk; \
} while (0)

// Load A fragments for phase (ks32, mh): rows wr*128+mh*64+mt*32+l31, both ks16 chunks.
#define RD_A(buf, ks, mh) do { \
    _Pragma("unroll") for (int _mt = 0; _mt < 2; ++_mt) { \
        int _row = wr * 128 + (mh) * 64 + _mt * 32 + l31; \
        int _key = (_row >> 1) & 3; \
        aK0[_mt] = *(const bf16x8*)&sA[buf][ks][_row * 32 + ((lh     ^ _key)) * 8]; \
        aK1[_mt] = *(const bf16x8*)&sA[buf][ks][_row * 32 + (((2+lh) ^ _key)) * 8]; \
    } \
} while (0)

#define RD_B(buf, ks) do { \
    _Pragma("unroll") for (int _nt = 0; _nt < 2; ++_nt) { \
        int _row = wc * 64 + _nt * 32 + l31; \
        int _key = (_row >> 1) & 3; \
        bK0[_nt] = *(const bf16x8*)&sB[buf][ks][_row * 32 + ((lh     ^ _key)) * 8]; \
        bK1[_nt] = *(const bf16x8*)&sB[buf][ks][_row * 32 + (((2+lh) ^ _key)) * 8]; \
    } \
} while (0)

// 8 x mfma_f32_32x32x16_bf16: (2 mt x 2 nt) x 2 ks16, accumulate into acc[mh*2+mt][nt]
#define MFMA8(mh) do { \
    __builtin_amdgcn_s_setprio(1); \
    _Pragma("unroll") for (int _mt = 0; _mt < 2; ++_mt) \
    _Pragma("unroll") for (int _nt = 0; _nt < 2; ++_nt) \
        acc[(mh)*2+_mt][_nt] = __builtin_amdgcn_mfma_f32_32x32x16_bf16(aK0[_mt], bK0[_nt], acc[(mh)*2+_mt][_nt], 0, 0, 0); \
    _Pragma("unroll") for (int _mt = 0; _mt < 2; ++_mt) \
    _Pragma("unroll") for (int _nt = 0; _nt < 2; ++_nt) \
        acc[(mh)*2+_mt][_nt] = __builtin_amdgcn_mfma_f32_32x32x16_bf16(aK1[_mt], bK1[_nt], acc[(mh)*2+_mt][_nt], 0, 0, 0); \
    __builtin_amdgcn_s_setprio(0); \
} while (0)

    // ---------------- prologue (identical to R8) ----------------
    if constexpr (PASS == 1) {
        LOAD_A_F(gA0, gA1, gA2, gA3, 0, 0);
        LOAD_A_F(gB0, gB1, gB2, gB3, 0, 1);
        STAGE_B(0, 0, 0); STAGE_B(0, 0, 1);
        WRITE_A(0, 0, gA0, gA1, gA2, gA3);
        WRITE_A(0, 1, gB0, gB1, gB2, gB3);
        LOAD_A_F(gA0, gA1, gA2, gA3, 1, 0);
        LOAD_A_F(gB0, gB1, gB2, gB3, 1, 1);
        LGW();
        VMW(8);
        BAR();
    } else {
        STAGE_A_G(0, 0, 0); STAGE_B(0, 0, 0);
        STAGE_A_G(0, 0, 1); STAGE_B(0, 0, 1);
        VMW(4);
        BAR();
    }

    // ---------------- main loop: 8 iters x 2 K-tiles (R8 schedule) ----------------
    for (int i = 0; i < 8; ++i) {
        int t1 = 2 * i + 1;
        int t2 = 2 * i + 2; if (t2 > 15) t2 = 15;
        int t3 = 2 * i + 3; if (t3 > 15) t3 = 15;

        // ph0
        RD_A(0, 0, 0); RD_B(0, 0);
        if constexpr (PASS == 1) {
            WRITE_A(1, 0, gA0, gA1, gA2, gA3);
            LOAD_A_F(gA0, gA1, gA2, gA3, t2, 0);
            LGW();
        } else {
            STAGE_A_G(1, t1, 0);
        }
        BAR(); MFMA8(0); BAR();

        // ph1
        RD_A(0, 0, 1);
        STAGE_B(1, t1, 0);
        BAR(); MFMA8(1);
        if constexpr (PASS == 1) { VMW(6); } else { VMW(4); }
        BAR();

        // ph2
        RD_A(0, 1, 0); RD_B(0, 1);
        if constexpr (PASS == 1) {
            WRITE_A(1, 1, gB0, gB1, gB2, gB3);
            LOAD_A_F(gB0, gB1, gB2, gB3, t2, 1);
            LGW();
        } else {
            STAGE_A_G(1, t1, 1);
        }
        BAR(); MFMA8(0); BAR();

        // ph3
        RD_A(0, 1, 1);
        STAGE_B(1, t1, 1);
        BAR(); MFMA8(1);
        if constexpr (PASS == 1) { VMW(6); } else { VMW(4); }
        BAR();

        // ph4
        RD_A(1, 0, 0); RD_B(1, 0);
        if constexpr (PASS == 1) {
            WRITE_A(0, 0, gA0, gA1, gA2, gA3);
            LOAD_A_F(gA0, gA1, gA2, gA3, t3, 0);
            LGW();
        } else {
            STAGE_A_G(0, t2, 0);
        }
        BAR(); MFMA8(0); BAR();

        // ph5
        RD_A(1, 0, 1);
        STAGE_B(0, t2, 0);
        BAR(); MFMA8(1);
        if constexpr (PASS == 1) { VMW(6); } else { VMW(4); }
        BAR();

        // ph6
        RD_A(1, 1, 0); RD_B(1, 1);
        if constexpr (PASS == 1) {
            WRITE_A(0, 1, gB0, gB1, gB2, gB3);
            LOAD_A_F(gB0, gB1, gB2, gB3, t3, 1);
            LGW();
        } else {
            STAGE_A_G(0, t2, 1);
        }
        BAR(); MFMA8(0); BAR();

        // ph7
        RD_A(1, 1, 1);
        STAGE_B(0, t2, 1);
        BAR(); MFMA8(1);
        if constexpr (PASS == 1) { VMW(6); } else { VMW(4); }
        BAR();
    }

    // ---------------- epilogue (32x32 C/D layout) ----------------
    int rowb = brow * 256 + wr * 128 + 4 * lh;
#pragma unroll
    for (int nt = 0; nt < 2; ++nt) {
        int col = bcol * 256 + wc * 64 + nt * 32 + l31;
        float cm, ca;
        if constexpr (PASS == 1) { cm = wst[col]; ca = bias[col]; }
        else                     { cm = dco[col]; ca = ad2[col]; }
#pragma unroll
        for (int mt = 0; mt < 4; ++mt) {
#pragma unroll
            for (int r = 0; r < 16; ++r) {
                int row = rowb + mt * 32 + (r & 3) + 8 * (r >> 2);
                size_t idx = (size_t)row * DDIM + col;
                float v = acc[mt][nt][r];
                if constexpr (PASS == 1) {
                    v = (v + ca) * cm;
                    Cb[idx] = __float2bfloat16(v);
                } else {
                    v = v * cm + ca;
                    v = (v >= 0.f) ? v : 0.01f * v;
                    Cf[idx] = v;
                }
            }
        }
    }
#undef STAGE_B
#undef STAGE_A_G
#undef LOAD_A_F
#undef WRITE_A
#undef RD_A
#undef RD_B
#undef MFMA8
}

extern "C" void kernel_launch(void* const* d_in, const int* in_sizes, int n_in,
                              void* d_out, int out_size, void* d_ws, size_t ws_size,
                              hipStream_t stream) {
    const float* x  = (const float*)d_in[0];
    const float* w  = (const float*)d_in[1];
    const float* W  = (const float*)d_in[2];
    const float* b  = (const float*)d_in[3];
    const float* ns = (const float*)d_in[4];
    const float* nr = (const float*)d_in[5];
    float* out = (float*)d_out;

    float* dco = (float*)d_ws;
    float* ad2 = dco + DDIM;
    bf16*  Wb  = (bf16*)((char*)d_ws + 8192);
    bf16*  t   = (bf16*)((char*)d_ws + 8192 + 2097152);

    int M = in_sizes[0] / DDIM;                     // 65536
    int grid = (M / 256) * (DDIM / 256);            // 1024

    prep_kernel<<<DDIM, 64, 0, stream>>>(W, w, b, ns, nr, dco, ad2, Wb);
    gemm32<1><<<grid, 512, 0, stream>>>(x, nullptr, Wb, w, b, dco, ad2, t, nullptr);
    gemm32<2><<<grid, 512, 0, stream>>>(nullptr, t, Wb, w, b, dco, ad2, nullptr, out);
}